// Round 1
// baseline (31361.526 us; speedup 1.0000x reference)
//
#include <hip/hip_runtime.h>
#include <hip/hip_cooperative_groups.h>

namespace cg = cooperative_groups;

#define B_ 64
#define T_ 1024
#define I_ 512
#define H_ 768
#define O_ 512
#define G4 3072          // 4*H
#define KC 1280          // I + H
#define JB 16            // j-columns per workgroup
#define NWG 48           // workgroups per direction (H/JB)

typedef short short8 __attribute__((ext_vector_type(8)));
typedef float f32x4 __attribute__((ext_vector_type(4)));

// ws layout (bytes):
//   x_bf   : [T][B][I] bf16 (fwd order; bwd reads reversed t)  = 67,108,864 B
//   wcat   : [2][3072][1280] bf16 ([row][k], k = Wx|Wh fused)  = 15,728,640 B
//   h_buf  : [2 dir][2 ring][B][H] bf16                        =    393,216 B
#define XBF_BYTES  (67108864)
#define WCAT_BYTES (15728640)

__device__ __forceinline__ unsigned short f32_to_bf16(float f) {
    union { float f; unsigned int u; } v; v.f = f;
    unsigned int r = v.u + 0x7fffu + ((v.u >> 16) & 1u);
    return (unsigned short)(r >> 16);
}

__device__ __forceinline__ float sigmoid_f(float x) {
    return 1.0f / (1.0f + __expf(-x));
}
__device__ __forceinline__ float tanh_f(float x) {
    float e = __expf(2.0f * x);
    return 1.0f - 2.0f / (e + 1.0f);
}

// ---- prep: x (B,T,I) fp32 -> x_bf (T,B,I) bf16 -------------------------------
__global__ void prep_x_kernel(const float* __restrict__ x, unsigned short* __restrict__ xb) {
    const size_t n4 = (size_t)T_ * B_ * I_ / 4;
    for (size_t i = (size_t)blockIdx.x * blockDim.x + threadIdx.x; i < n4;
         i += (size_t)gridDim.x * blockDim.x) {
        size_t d = i * 4;
        int k = (int)(d % I_);
        size_t r = d / I_;
        int b = (int)(r % B_);
        int t = (int)(r / B_);
        const float4 v = *(const float4*)(x + ((size_t)b * T_ + t) * I_ + k);
        ushort4 o;
        o.x = f32_to_bf16(v.x); o.y = f32_to_bf16(v.y);
        o.z = f32_to_bf16(v.z); o.w = f32_to_bf16(v.w);
        *(ushort4*)(xb + d) = o;
    }
}

// ---- prep: weights fp32 -> wcat bf16 [dir][row][k], zero h ring --------------
__global__ void prep_w_kernel(const float* __restrict__ Wx_f, const float* __restrict__ Wh_f,
                              const float* __restrict__ Wx_b, const float* __restrict__ Wh_b,
                              unsigned short* __restrict__ wcat, unsigned short* __restrict__ h_buf) {
    const size_t n = (size_t)2 * G4 * KC;   // 7,864,320
    for (size_t i = (size_t)blockIdx.x * blockDim.x + threadIdx.x; i < n;
         i += (size_t)gridDim.x * blockDim.x) {
        int k = (int)(i % KC);
        size_t r = i / KC;
        int row = (int)(r % G4);
        int dir = (int)(r / G4);
        const float* Wx = dir ? Wx_b : Wx_f;
        const float* Wh = dir ? Wh_b : Wh_f;
        float v = (k < I_) ? Wx[(size_t)row * I_ + k] : Wh[(size_t)row * H_ + (k - I_)];
        wcat[i] = f32_to_bf16(v);
        if (i < (size_t)2 * 2 * B_ * H_) h_buf[i] = 0;
    }
}

// ---- persistent cooperative BiLSTM recurrence --------------------------------
// grid = 96 wgs (2 dirs x 48 j-blocks), 512 threads (8 waves: gate x mhalf).
// Per step: z(64 x 64cols) = [x_t|h] @ Wcat^T + bias via mfma 16x16x32 bf16,
// gate math fp32, c in LDS, h -> bf16 ring buffer, grid.sync().
__global__ void __launch_bounds__(512, 1)
bilstm_kernel(const float* __restrict__ bias_f, const float* __restrict__ bias_b,
              const unsigned short* __restrict__ x_bf, const unsigned short* __restrict__ wcat,
              unsigned short* h_buf, float* d_out) {
    __shared__ float z_lds[4][64][17];   // [gate][b][j], padded
    __shared__ float c_tile[64][16];     // fp32 cell state, persistent across steps

    const int tid   = threadIdx.x;
    const int wg    = blockIdx.x;
    const int dir   = wg / NWG;
    const int jblk  = wg % NWG;
    const int j0    = jblk * JB;
    const int wave  = tid >> 6;
    const int lane  = tid & 63;
    const int gate  = wave & 3;      // 0=f 1=i 2=g 3=o
    const int mhalf = wave >> 2;     // 0..1 -> m-tiles {2m,2m+1}
    const int quad  = lane >> 4;
    const int lrow  = lane & 15;

    for (int i = tid; i < 64 * 16; i += 512) c_tile[i >> 4][i & 15] = 0.0f;

    const float* bptr = dir ? bias_b : bias_f;
    const float bias_r = bptr[gate * H_ + j0 + lrow];

    // B-operand base: W row (= z column) for this lane, contiguous in k
    const unsigned short* wk =
        wcat + ((size_t)dir * G4 + (size_t)gate * H_ + j0 + lrow) * KC + quad * 8;

    const int m0 = mhalf * 32 + lrow;   // batch row of first m-tile
    const int m1 = m0 + 16;

    cg::grid_group grid = cg::this_grid();
    __syncthreads();

    for (int t = 0; t < T_; ++t) {
        const int pb = (t + 1) & 1;   // ring slot holding h_{t-1}
        const int cb = t & 1;         // ring slot for h_t
        const int tx = dir ? (T_ - 1 - t) : t;

        f32x4 acc0; acc0[0] = bias_r; acc0[1] = bias_r; acc0[2] = bias_r; acc0[3] = bias_r;
        f32x4 acc1 = acc0;

        // x-projection part: K = 0..511
        const unsigned short* xrow0 = x_bf + ((size_t)tx * B_ + m0) * I_ + quad * 8;
        const unsigned short* xrow1 = x_bf + ((size_t)tx * B_ + m1) * I_ + quad * 8;
#pragma unroll
        for (int ks = 0; ks < 16; ++ks) {
            short8 a0 = *(const short8*)(xrow0 + ks * 32);
            short8 a1 = *(const short8*)(xrow1 + ks * 32);
            short8 bf = *(const short8*)(wk + ks * 32);
            acc0 = __builtin_amdgcn_mfma_f32_16x16x32_bf16(a0, bf, acc0, 0, 0, 0);
            acc1 = __builtin_amdgcn_mfma_f32_16x16x32_bf16(a1, bf, acc1, 0, 0, 0);
        }
        // h-recurrence part: K = 512..1279
        const unsigned short* hrow0 = h_buf + ((size_t)(dir * 2 + pb) * B_ + m0) * H_ + quad * 8;
        const unsigned short* hrow1 = hrow0 + 16 * H_;
        const unsigned short* wk2 = wk + I_;
#pragma unroll
        for (int ks = 0; ks < 24; ++ks) {
            short8 a0 = *(const short8*)(hrow0 + ks * 32);
            short8 a1 = *(const short8*)(hrow1 + ks * 32);
            short8 bf = *(const short8*)(wk2 + ks * 32);
            acc0 = __builtin_amdgcn_mfma_f32_16x16x32_bf16(a0, bf, acc0, 0, 0, 0);
            acc1 = __builtin_amdgcn_mfma_f32_16x16x32_bf16(a1, bf, acc1, 0, 0, 0);
        }

        // z -> LDS (C layout: col = lane&15, row = quad*4 + reg, + 16*mtile)
#pragma unroll
        for (int r = 0; r < 4; ++r) {
            z_lds[gate][mhalf * 32 + quad * 4 + r][lrow]      = acc0[r];
            z_lds[gate][mhalf * 32 + 16 + quad * 4 + r][lrow] = acc1[r];
        }
        __syncthreads();

        // gates: 1024 (b,j) items over 512 threads
#pragma unroll
        for (int rep = 0; rep < 2; ++rep) {
            int idx = tid + rep * 512;
            int b = idx >> 4, j = idx & 15;
            float f  = sigmoid_f(z_lds[0][b][j]);
            float ii = sigmoid_f(z_lds[1][b][j]);
            float g  = tanh_f(z_lds[2][b][j]);
            float o  = sigmoid_f(z_lds[3][b][j]);
            float c  = f * c_tile[b][j] + ii * g;
            c_tile[b][j] = c;
            float h = o * tanh_f(c);
            h_buf[((size_t)(dir * 2 + cb) * B_ + b) * H_ + j0 + j] = f32_to_bf16(h);
            if (t == T_ - 1) {
                // d_out: [out 32768][h_fwd 49152][c_fwd 49152][h_bwd 49152][c_bwd 49152]
                int hoff = 32768 + dir * 98304;
                d_out[hoff + b * H_ + j0 + j] = h;
                d_out[hoff + 49152 + b * H_ + j0 + j] = c;
            }
        }
        grid.sync();
    }
}

// ---- epilogue: out = [h_fwd|h_bwd] @ Why^T + by ------------------------------
__global__ void proj_kernel(float* __restrict__ out, const float* __restrict__ Why,
                            const float* __restrict__ by) {
    __shared__ float hc[2 * H_];
    int b = blockIdx.x;
    const float* hf = out + 32768 + b * H_;
    const float* hb = out + 32768 + 98304 + b * H_;
    for (int i = threadIdx.x; i < H_; i += 256) { hc[i] = hf[i]; hc[H_ + i] = hb[i]; }
    __syncthreads();
    for (int o = threadIdx.x; o < O_; o += 256) {
        const float* wr = Why + (size_t)o * (2 * H_);
        float s = by[o];
        for (int k = 0; k < 2 * H_; k += 4) {
            float4 w = *(const float4*)(wr + k);
            s += w.x * hc[k] + w.y * hc[k + 1] + w.z * hc[k + 2] + w.w * hc[k + 3];
        }
        out[b * O_ + o] = s;
    }
}

extern "C" void kernel_launch(void* const* d_in, const int* in_sizes, int n_in,
                              void* d_out, int out_size, void* d_ws, size_t ws_size,
                              hipStream_t stream) {
    const float* x    = (const float*)d_in[0];
    const float* Wx_f = (const float*)d_in[1];
    const float* Wh_f = (const float*)d_in[2];
    const float* b_f  = (const float*)d_in[3];
    const float* Wx_b = (const float*)d_in[4];
    const float* Wh_b = (const float*)d_in[5];
    const float* b_b  = (const float*)d_in[6];
    const float* Why  = (const float*)d_in[7];
    const float* by   = (const float*)d_in[8];
    float* out = (float*)d_out;

    char* ws = (char*)d_ws;
    unsigned short* x_bf  = (unsigned short*)(ws);
    unsigned short* wcat  = (unsigned short*)(ws + XBF_BYTES);
    unsigned short* h_buf = (unsigned short*)(ws + XBF_BYTES + WCAT_BYTES);

    prep_x_kernel<<<4096, 256, 0, stream>>>(x, x_bf);
    prep_w_kernel<<<4096, 256, 0, stream>>>(Wx_f, Wh_f, Wx_b, Wh_b, wcat, h_buf);

    void* args[] = {(void*)&b_f, (void*)&b_b, (void*)&x_bf, (void*)&wcat,
                    (void*)&h_buf, (void*)&out};
    hipLaunchCooperativeKernel((void*)bilstm_kernel, dim3(2 * NWG), dim3(512), args, 0, stream);

    proj_kernel<<<B_, 256, 0, stream>>>(out, Why, by);
}

// Round 3
// 10610.898 us; speedup vs baseline: 2.9556x; 2.9556x over previous
//
#include <hip/hip_runtime.h>
#include <hip/hip_cooperative_groups.h>

namespace cg = cooperative_groups;

#define B_ 64
#define T_ 1024
#define I_ 512
#define H_ 768
#define O_ 512
#define G4 3072          // 4*H
#define JB 16            // j-columns per workgroup
#define NWG 48           // workgroups per direction (H/JB)
#define NWGS 96          // total workgroups

typedef short short8 __attribute__((ext_vector_type(8)));
typedef float f32x4 __attribute__((ext_vector_type(4)));

// ws layout (bytes):
//   xb  : [T][64 kb][64 b][8] bf16 (k-blocked)            = 67,108,864 B
//   w2  : [2 dir][160 kb][3072 row][8] bf16 (k-blocked)   = 15,728,640 B
//   h2  : [2 dir][2 ring][96 kb][64 b][8] bf16            =    393,216 B
//   bar : unsigned                                         =          4 B
#define XBF_BYTES  (67108864)
#define WCAT_BYTES (15728640)
#define HBUF_BYTES (393216)

__device__ __forceinline__ unsigned short f32_to_bf16(float f) {
    union { float f; unsigned int u; } v; v.f = f;
    unsigned int r = v.u + 0x7fffu + ((v.u >> 16) & 1u);
    return (unsigned short)(r >> 16);
}
__device__ __forceinline__ float sigmoid_f(float x) { return 1.0f / (1.0f + __expf(-x)); }
__device__ __forceinline__ float tanh_f(float x) {
    float e = __expf(2.0f * x);
    return 1.0f - 2.0f / (e + 1.0f);
}

// ---- prep: x (B,T,I) fp32 -> xb [t][kb][b][8] bf16 ---------------------------
// thread i handles 8 consecutive k: reads are fully linear (x offset = 8*i).
__global__ void prep_x_kernel(const float* __restrict__ x, unsigned short* __restrict__ xb) {
    const size_t n = (size_t)B_ * T_ * 64;   // 4,194,304 chunks
    for (size_t i = (size_t)blockIdx.x * blockDim.x + threadIdx.x; i < n;
         i += (size_t)gridDim.x * blockDim.x) {
        int b  = (int)(i >> 16);
        int t  = (int)((i >> 6) & 1023);
        int kb = (int)(i & 63);
        const float4 v0 = *(const float4*)(x + i * 8);
        const float4 v1 = *(const float4*)(x + i * 8 + 4);
        short8 o;
        o[0] = (short)f32_to_bf16(v0.x); o[1] = (short)f32_to_bf16(v0.y);
        o[2] = (short)f32_to_bf16(v0.z); o[3] = (short)f32_to_bf16(v0.w);
        o[4] = (short)f32_to_bf16(v1.x); o[5] = (short)f32_to_bf16(v1.y);
        o[6] = (short)f32_to_bf16(v1.z); o[7] = (short)f32_to_bf16(v1.w);
        *(short8*)(xb + (((size_t)t * 64 + kb) * 64 + b) * 8) = o;
    }
}

// ---- prep: weights fp32 -> w2 k-blocked bf16; zero h ring + barrier ----------
__global__ void prep_w_kernel(const float* __restrict__ Wx_f, const float* __restrict__ Wh_f,
                              const float* __restrict__ Wx_b, const float* __restrict__ Wh_b,
                              unsigned short* __restrict__ w2, unsigned short* __restrict__ h2,
                              unsigned* __restrict__ bar) {
    const size_t n = (size_t)2 * G4 * 160;   // 983,040 chunks of 8 k
    for (size_t i = (size_t)blockIdx.x * blockDim.x + threadIdx.x; i < n;
         i += (size_t)gridDim.x * blockDim.x) {
        int dir = (int)(i / 491520);
        int r2  = (int)(i % 491520);
        int row = r2 / 160;
        int kb  = r2 % 160;
        const float* Wx = dir ? Wx_b : Wx_f;
        const float* Wh = dir ? Wh_b : Wh_f;
        const float* src = (kb < 64) ? (Wx + (size_t)row * I_ + kb * 8)
                                     : (Wh + (size_t)row * H_ + (kb - 64) * 8);
        const float4 v0 = *(const float4*)(src);
        const float4 v1 = *(const float4*)(src + 4);
        short8 o;
        o[0] = (short)f32_to_bf16(v0.x); o[1] = (short)f32_to_bf16(v0.y);
        o[2] = (short)f32_to_bf16(v0.z); o[3] = (short)f32_to_bf16(v0.w);
        o[4] = (short)f32_to_bf16(v1.x); o[5] = (short)f32_to_bf16(v1.y);
        o[6] = (short)f32_to_bf16(v1.z); o[7] = (short)f32_to_bf16(v1.w);
        *(short8*)(w2 + (((size_t)dir * 160 + kb) * G4 + row) * 8) = o;
        if (i < 24576) {   // zero all 4 h ring slots (393,216 B)
            short8 z = {0,0,0,0,0,0,0,0};
            *(short8*)(h2 + i * 8) = z;
        }
        if (i == 0) *bar = 0u;
    }
}

// ---- persistent BiLSTM recurrence with custom barrier ------------------------
// 96 wgs (2 dir x 48 j-blocks) x 512 thr (8 waves: gate x mhalf).
// Per step: x-part MFMA overlapped with barrier wait; h-part weights register-
// resident; h exchanged through global bf16 k-blocked ring; monotonic counter
// barrier (one agent atomicAdd per wg per step).
__global__ void __launch_bounds__(512, 2)
bilstm_kernel(const float* __restrict__ bias_f, const float* __restrict__ bias_b,
              const unsigned short* __restrict__ xb, const unsigned short* __restrict__ w2,
              unsigned short* h2, unsigned* bar, float* d_out) {
    __shared__ float z_lds[4][64][17];
    __shared__ float c_tile[64][16];

    const int tid   = threadIdx.x;
    const int wg    = blockIdx.x;
    const int dir   = wg / NWG;
    const int j0    = (wg % NWG) * JB;
    const int wave  = tid >> 6;
    const int lane  = tid & 63;
    const int gate  = wave & 3;      // f,i,g,o
    const int mhalf = wave >> 2;
    const int quad  = lane >> 4;
    const int lrow  = lane & 15;

    for (int i = tid; i < 1024; i += 512) c_tile[i >> 4][i & 15] = 0.0f;

    const float bias_r = (dir ? bias_b : bias_f)[gate * H_ + j0 + lrow];
    const int m0 = mhalf * 32 + lrow;
    const int wrow = gate * H_ + j0 + lrow;

    // x-weight base (kb = quad, advances by 4 per ks → stride 4*G4*8 shorts)
    const unsigned short* wx = w2 + (((size_t)dir * 160 + quad) * G4 + wrow) * 8;
    // h-weights: register-resident, constant over all steps (kb = 64 + ks*4 + quad)
    short8 wh[24];
#pragma unroll
    for (int ks = 0; ks < 24; ++ks)
        wh[ks] = *(const short8*)(w2 + (((size_t)dir * 160 + 64 + ks * 4 + quad) * G4 + wrow) * 8);

    __syncthreads();

    for (int t = 0; t < T_; ++t) {
        const int pb = (t + 1) & 1;
        const int cb = t & 1;
        const int tx = dir ? (T_ - 1 - t) : t;

        f32x4 acc0; acc0[0] = bias_r; acc0[1] = bias_r; acc0[2] = bias_r; acc0[3] = bias_r;
        f32x4 acc1 = acc0;

        // ---- x-part (independent of h_{t-1}; overlaps other wgs' arrival) ----
        const unsigned short* xa = xb + (((size_t)tx * 64 + quad) * 64 + m0) * 8;
#pragma unroll
        for (int ks = 0; ks < 16; ++ks) {
            short8 a0 = *(const short8*)(xa + ks * 2048);
            short8 a1 = *(const short8*)(xa + ks * 2048 + 128);
            short8 bf = *(const short8*)(wx + (size_t)ks * 4 * G4 * 8);
            acc0 = __builtin_amdgcn_mfma_f32_16x16x32_bf16(a0, bf, acc0, 0, 0, 0);
            acc1 = __builtin_amdgcn_mfma_f32_16x16x32_bf16(a1, bf, acc1, 0, 0, 0);
        }

        // ---- wait for all wgs to have finished step t-1 ----
        if (tid == 0) {
            const unsigned tgt = (unsigned)(NWGS * t);
            while (__hip_atomic_load(bar, __ATOMIC_RELAXED, __HIP_MEMORY_SCOPE_AGENT) < tgt)
                __builtin_amdgcn_s_sleep(1);
            __builtin_amdgcn_fence(__ATOMIC_ACQUIRE, "agent");
        }
        __syncthreads();

        // ---- h-part: K = 768 recurrent ----
        const unsigned short* ha = h2 + ((size_t)(dir * 2 + pb) * 96 + quad) * 512 + m0 * 8;
#pragma unroll
        for (int ks = 0; ks < 24; ++ks) {
            short8 a0 = *(const short8*)(ha + ks * 2048);
            short8 a1 = *(const short8*)(ha + ks * 2048 + 128);
            acc0 = __builtin_amdgcn_mfma_f32_16x16x32_bf16(a0, wh[ks], acc0, 0, 0, 0);
            acc1 = __builtin_amdgcn_mfma_f32_16x16x32_bf16(a1, wh[ks], acc1, 0, 0, 0);
        }

        // z -> LDS (C layout: col=lane&15, row=quad*4+reg)
#pragma unroll
        for (int r = 0; r < 4; ++r) {
            z_lds[gate][mhalf * 32 + quad * 4 + r][lrow]      = acc0[r];
            z_lds[gate][mhalf * 32 + 16 + quad * 4 + r][lrow] = acc1[r];
        }
        __syncthreads();

        // ---- gates ----
        unsigned short* hw = h2 + (size_t)(dir * 2 + cb) * 49152;
#pragma unroll
        for (int rep = 0; rep < 2; ++rep) {
            int idx = tid + rep * 512;
            int b = idx >> 4, j = idx & 15;
            float f  = sigmoid_f(z_lds[0][b][j]);
            float ii = sigmoid_f(z_lds[1][b][j]);
            float g  = tanh_f(z_lds[2][b][j]);
            float o  = sigmoid_f(z_lds[3][b][j]);
            float c  = f * c_tile[b][j] + ii * g;
            c_tile[b][j] = c;
            float h = o * tanh_f(c);
            int jj = j0 + j;
            hw[((jj >> 3) * 64 + b) * 8 + (jj & 7)] = f32_to_bf16(h);
            if (t == T_ - 1) {
                int hoff = 32768 + dir * 98304;
                d_out[hoff + b * H_ + jj] = h;
                d_out[hoff + 49152 + b * H_ + jj] = c;
            }
        }
        __syncthreads();   // drains vmcnt per wave → h stores are in L2

        // ---- arrive (release writes back dirty lines to coherence point) ----
        if (tid == 0)
            __hip_atomic_fetch_add(bar, 1u, __ATOMIC_RELEASE, __HIP_MEMORY_SCOPE_AGENT);
    }
}

// ---- epilogue: out = [h_fwd|h_bwd] @ Why^T + by ------------------------------
__global__ void proj_kernel(float* __restrict__ out, const float* __restrict__ Why,
                            const float* __restrict__ by) {
    __shared__ float hc[2 * H_];
    int b = blockIdx.x;
    const float* hf = out + 32768 + b * H_;
    const float* hb = out + 32768 + 98304 + b * H_;
    for (int i = threadIdx.x; i < H_; i += 256) { hc[i] = hf[i]; hc[H_ + i] = hb[i]; }
    __syncthreads();
    for (int o = threadIdx.x; o < O_; o += 256) {
        const float* wr = Why + (size_t)o * (2 * H_);
        float s = by[o];
        for (int k = 0; k < 2 * H_; k += 4) {
            float4 w = *(const float4*)(wr + k);
            s += w.x * hc[k] + w.y * hc[k + 1] + w.z * hc[k + 2] + w.w * hc[k + 3];
        }
        out[b * O_ + o] = s;
    }
}

extern "C" void kernel_launch(void* const* d_in, const int* in_sizes, int n_in,
                              void* d_out, int out_size, void* d_ws, size_t ws_size,
                              hipStream_t stream) {
    const float* x    = (const float*)d_in[0];
    const float* Wx_f = (const float*)d_in[1];
    const float* Wh_f = (const float*)d_in[2];
    const float* b_f  = (const float*)d_in[3];
    const float* Wx_b = (const float*)d_in[4];
    const float* Wh_b = (const float*)d_in[5];
    const float* b_b  = (const float*)d_in[6];
    const float* Why  = (const float*)d_in[7];
    const float* by   = (const float*)d_in[8];
    float* out = (float*)d_out;

    char* ws = (char*)d_ws;
    unsigned short* xbp = (unsigned short*)(ws);
    unsigned short* w2  = (unsigned short*)(ws + XBF_BYTES);
    unsigned short* h2  = (unsigned short*)(ws + XBF_BYTES + WCAT_BYTES);
    unsigned*       bar = (unsigned*)(ws + XBF_BYTES + WCAT_BYTES + HBUF_BYTES);

    prep_x_kernel<<<8192, 256, 0, stream>>>(x, xbp);
    prep_w_kernel<<<4096, 256, 0, stream>>>(Wx_f, Wh_f, Wx_b, Wh_b, w2, h2, bar);

    void* args[] = {(void*)&b_f, (void*)&b_b, (void*)&xbp, (void*)&w2,
                    (void*)&h2, (void*)&bar, (void*)&out};
    hipLaunchCooperativeKernel((void*)bilstm_kernel, dim3(NWGS), dim3(512), args, 0, stream);

    proj_kernel<<<B_, 256, 0, stream>>>(out, Why, by);
}